// Round 8
// baseline (94.697 us; speedup 1.0000x reference)
//
#include <hip/hip_runtime.h>
#include <hip/hip_bf16.h>
#include <math.h>

// Batch-hard triplet loss, B=8192, D=128, fp32 in.
// dist^2[i,j] = rowterm[i] + colterm[j] - 2*dot(e1[i], e2[j])
// sqrt & max/min commute -> track max/min of (colterm - 2*dot); dot on bf16
// matrix cores. Target folded into cpos/cneg (finite +-1e30 sentinels).
//
// R15 vs R14: occupancy, not schedule. R12's destall and R14's counted-
// vmcnt were BOTH ~neutral (91.1 -> 90.0) -> zero-overlap pipe-sum (~11us)
// vs observed (~32us) says 2/3 of tile time is empty-issue stall at 2
// blocks/CU (512 blocks, occupancy 27%). The only lever that ever moved
// this kernel is resident blocks (R9 16%->R12 28% = 46->34us). R15:
// SPLITS=16 -> 1024 blocks, 8 panels/block, LDS 2x16.9+4 = 37.9 KB ->
// 3 blocks/CU under __launch_bounds__(256,3) (12 waves/CU). Same panel-
// slots/CU, 50% more concurrent blocks to hide barrier+DMA waits.
// Pipeline ledger (wait-then-barrier), swizzle, MFMA order byte-identical
// to R14 -> absmax 0.

#define DDIM   128
#define SPLITS 16
#define MARGIN 0.2f
#define EPS    1e-6f
#define SENT   1e30f

#define CHUNK_PITCH  1056          // 1024 B data (4 rows x 256 B) + 32 B pad
#define PANEL_CHUNKS 16            // 64 rows per panel
#define PANEL_BYTES  (PANEL_CHUNKS * CHUNK_PITCH)   // 16896 B
#define CPCN_BYTES   (1024 * 4)                     // 512 cp + 512 cn floats

typedef unsigned short ushort_t;
typedef __attribute__((ext_vector_type(8))) short short8;
typedef __attribute__((ext_vector_type(4))) float f32x4;
typedef __attribute__((ext_vector_type(4))) unsigned short ushort4_t;

__device__ __forceinline__ ushort_t f2bf(float f) {   // fp32 -> bf16 RNE
    unsigned int u = __float_as_uint(f);
    u = (u + 0x7FFFu + ((u >> 16) & 1u)) >> 16;
    return (ushort_t)u;
}

__device__ __forceinline__ void g2lds16(const void* g, void* lds) {
    // per-lane global src; wave-uniform lds base, lane i's 16 B at lds+i*16
    __builtin_amdgcn_global_load_lds(
        (const __attribute__((address_space(1))) unsigned int*)g,
        (__attribute__((address_space(3))) unsigned int*)lds,
        16, 0, 0);
}

// ---- kernel 1: bf16 convert + exact fp32 row stats + zero control vars ----
// 8 lanes per row; fully coalesced float4/ushort4. e1b stores bf16(-2*x)
// (exact scale: exp+1 & sign) so MFMA directly yields -2*dot.
__global__ void prep_kernel(const float* __restrict__ e1, const float* __restrict__ e2,
                            const int* __restrict__ target,
                            ushort_t* __restrict__ e1b, ushort_t* __restrict__ e2b,
                            float* __restrict__ rowterm,
                            float* __restrict__ cpos, float* __restrict__ cneg,
                            float* __restrict__ redsum, int* __restrict__ ticket, int B) {
    if (blockIdx.x == 0) {
        if (threadIdx.x == 0) { redsum[0] = 0.f; redsum[1] = 0.f; }
        else if (threadIdx.x == 1) *ticket = 0;
    }
    int gr  = blockIdx.x * 32 + (threadIdx.x >> 3);     // 0..2B-1
    int seg = threadIdx.x & 7;
    bool first = gr < B;
    int r = first ? gr : gr - B;
    const float* src = (first ? e1 : e2) + (size_t)r * DDIM;
    ushort_t*    dst = (first ? e1b : e2b) + (size_t)r * DDIM;
    const float sc = first ? -2.f : 1.f;
    float s = 0.f, n = 0.f;
    #pragma unroll
    for (int it = 0; it < 4; ++it) {
        int e0 = (seg + it * 8) * 4;
        float4 v = *(const float4*)(src + e0);
        ushort4_t o;
        o.x = f2bf(sc * v.x); o.y = f2bf(sc * v.y);
        o.z = f2bf(sc * v.z); o.w = f2bf(sc * v.w);
        *(ushort4_t*)(dst + e0) = o;
        s += v.x + v.y + v.z + v.w;
        n += v.x * v.x + v.y * v.y + v.z * v.z + v.w * v.w;
    }
    #pragma unroll
    for (int m = 1; m <= 4; m <<= 1) {                  // 8-lane group reduce
        s += __shfl_xor(s, m, 64);
        n += __shfl_xor(n, m, 64);
    }
    if (seg == 0) {
        if (first) {
            rowterm[r] = n + 2.f * EPS * s + (float)DDIM * EPS * EPS;
        } else {
            float ct = n - 2.f * EPS * s;
            int tg = target[r];
            cpos[r] = (tg == 1) ? ct : -SENT;
            cneg[r] = (tg == 0) ? ct :  SENT;
        }
    }
}

// stage a 64-row bf16 panel (rows = cols of C) via DMA. Wave w stages rows
// [w*16, w*16+16) = chunks 4w..4w+3. Source slot pre-swizzled: slot low-2
// bits XOR chunk-local row, so linear DMA lands the swizzled layout.
__device__ __forceinline__ void stage_panel(const ushort_t* __restrict__ rowBase,
                                            unsigned char* __restrict__ lds,
                                            int w, int l, int sl) {
    const ushort_t* g = rowBase + (size_t)(w * 16 + (l >> 4)) * DDIM + sl * 8;
    unsigned char* lp = lds + (w * 4) * CHUNK_PITCH;
    #pragma unroll
    for (int it = 0; it < 4; ++it)
        g2lds16(g + it * 4 * DDIM, lp + it * CHUNK_PITCH);
}

// ---- kernel 2: streamed 64-col panels, counted-vmcnt pipeline -----------
// grid (B/128, SPLITS=16), block 256 = 4 waves. Block: 128 rows x 512 cols
// as 8 panels of 64 cols, double-buffered. Wave w: rows (w>>1)*64..+64,
// cols (w&1)*32..+32 of each panel. A (K=128) in registers from L2.
__global__ __launch_bounds__(256, 3)
void tile_kernel(const ushort_t* __restrict__ e1b, const ushort_t* __restrict__ e2b,
                 const float* __restrict__ cpos, const float* __restrict__ cneg,
                 float* __restrict__ pmp, float* __restrict__ nmp, int B) {
    __shared__ __align__(16) unsigned char smRaw[2 * PANEL_BYTES + CPCN_BYTES];
    unsigned char* Bs0  = smRaw;
    unsigned char* Bs1  = smRaw + PANEL_BYTES;
    float*         smCp = (float*)(smRaw + 2 * PANEL_BYTES);   // [512]
    float*         smCn = smCp + 512;                           // [512]

    const int tid = threadIdx.x;
    const int w   = tid >> 6;
    const int l   = tid & 63;
    const int lq  = l >> 4;          // quad 0..3
    const int lm  = l & 15;
    const int row0 = blockIdx.x * 128;
    const int col0 = blockIdx.y * 512;
    const int nPanels = 8;

    const int wr = (w >> 1) * 64;    // wave's row half
    const int wc = (w & 1) * 32;     // wave's col half within 64-col panel

    // staging source-slot swizzle: slot = (l&15) with low2 ^= (l>>4)
    const int sl = (l & 12) | ((l ^ (l >> 4)) & 3);

    // prologue DMAs: panel 0 + cpos/cneg slabs (one 1 KB DMA per wave:
    // w0/w1 -> cp halves, w2/w3 -> cn halves)
    stage_panel(e2b + (size_t)col0 * DDIM, Bs0, w, l, sl);
    {
        const float* csrc = (w < 2) ? cpos : cneg;
        float*       cdst = (w < 2) ? smCp : smCn;
        g2lds16(csrc + col0 + (w & 1) * 256 + l * 4, cdst + (w & 1) * 256);
    }

    // A fragments straight from global: row = row0+wr+i*16+lm,
    // elems [k4*32 + lq*8, +8). L2-resident (e1b = 2 MB, pre-scaled by -2).
    const ushort_t* aG = e1b + (size_t)(row0 + wr + lm) * DDIM + lq * 8;
    short8 afr[4][4];                // [i][k4]: 64 regs, K=128 resident
    #pragma unroll
    for (int i = 0; i < 4; ++i)
        #pragma unroll
        for (int k4 = 0; k4 < 4; ++k4)
            afr[i][k4] = *(const short8*)(aG + i * 16 * DDIM + k4 * 32);

    // B fragment read base: row R = wc + j*16 + lm; byte addr =
    //   (R>>2)*1056 + (R&3)*256 + (k4*4 + (lq^(R&3)))*16
    // (lane-constant base; + j*4*1056 + k4*64). lq^(lm&3) = swizzle inverse.
    const unsigned char* bLane = Bs0
        + ((wc >> 2) + (lm >> 2)) * CHUNK_PITCH
        + (lm & 3) * 256 + ((lq ^ (lm & 3)) * 16);

    float pm[4][4], nm[4][4];        // [i][r]: local row = wr + i*16 + lq*4 + r
    #pragma unroll
    for (int i = 0; i < 4; ++i)
        #pragma unroll
        for (int r = 0; r < 4; ++r) { pm[i][r] = -SENT; nm[i][r] = SENT; }

    __syncthreads();   // full drain: panel 0 + cpcn + afr all resident

    for (int p = 0; p < nPanels; ++p) {
        // WAR barrier: all waves done READING panel p-1 -> its parity
        // buffer may now be overwritten by stage(p+1). (p=0: prologue
        // __syncthreads already synced.)
        if (p) __builtin_amdgcn_s_barrier();

        if (p + 1 < nPanels) {
            // issue next panel's DMA; vmcnt queue = [stage(p):4, stage(p+1):4]
            stage_panel(e2b + (size_t)(col0 + (p + 1) * 64) * DDIM,
                        (p & 1) ? Bs0 : Bs1, w, l, sl);
            // retire exactly OWN stage(p) (4 oldest); stage(p+1) in flight
            asm volatile("s_waitcnt vmcnt(4)" ::: "memory");
        } else {
            asm volatile("s_waitcnt vmcnt(0)" ::: "memory");
        }
        // RAW barrier: every wave has retired ITS stage(p) loads, so the
        // whole panel p (all 4 waves' rows) is resident before any read.
        __builtin_amdgcn_s_barrier();

        const unsigned char* bl = bLane + (p & 1) * PANEL_BYTES;

        f32x4 accA[4], accB[4];      // j=0 / j=1 accumulators (32 regs)
        #pragma unroll
        for (int i = 0; i < 4; ++i) {
            accA[i] = (f32x4){0.f, 0.f, 0.f, 0.f};
            accB[i] = (f32x4){0.f, 0.f, 0.f, 0.f};
        }

        #pragma unroll
        for (int k4 = 0; k4 < 4; ++k4) {
            const short8 b0 = *(const short8*)(bl + k4 * 64);
            const short8 b1 = *(const short8*)(bl + 4 * CHUNK_PITCH + k4 * 64);
            #pragma unroll
            for (int i = 0; i < 4; ++i)
                accA[i] = __builtin_amdgcn_mfma_f32_16x16x32_bf16(
                              afr[i][k4], b0, accA[i], 0, 0, 0);
            #pragma unroll
            for (int i = 0; i < 4; ++i)
                accB[i] = __builtin_amdgcn_mfma_f32_16x16x32_bf16(
                              afr[i][k4], b1, accB[i], 0, 0, 0);
        }

        // epilogue: acc = -2*dot; colterm from LDS (lgkm only -> vmcnt
        // ledger stays pure). Paired so clang fuses v_max3/v_min3.
        {
            const int lcb = p * 64 + wc + lm;            // C/D: col = lane&15
            const float cp0 = smCp[lcb],      cn0 = smCn[lcb];
            const float cp1 = smCp[lcb + 16], cn1 = smCn[lcb + 16];
            #pragma unroll
            for (int i = 0; i < 4; ++i)
                #pragma unroll
                for (int r = 0; r < 4; ++r) {
                    const float d0 = accA[i][r];
                    const float d1 = accB[i][r];
                    pm[i][r] = fmaxf(fmaxf(pm[i][r], d0 + cp0), d1 + cp1);
                    nm[i][r] = fminf(fminf(nm[i][r], d0 + cn0), d1 + cn1);
                }
        }
    }

    // intra-wave: reduce across the 16 column-lanes (rows fixed per (lq,r))
    #pragma unroll
    for (int m = 1; m < 16; m <<= 1) {
        #pragma unroll
        for (int i = 0; i < 4; ++i)
            #pragma unroll
            for (int r = 0; r < 4; ++r) {
                pm[i][r] = fmaxf(pm[i][r], __shfl_xor(pm[i][r], m, 64));
                nm[i][r] = fminf(nm[i][r], __shfl_xor(nm[i][r], m, 64));
            }
    }

    // cross-wave: pairs (0,1),(2,3) share rows over complementary col halves.
    // Overlay on Bs0 (last panel p=7 lives in Bs1; Bs0's readers done at
    // p=7's WAR barrier). Even waves read only after the __syncthreads.
    float* smP = (float*)smRaw;            // [128]
    float* smN = smP + 128;                // [128]
    if ((w & 1) == 1 && lm == 0) {
        #pragma unroll
        for (int i = 0; i < 4; ++i)
            #pragma unroll
            for (int r = 0; r < 4; ++r) {
                int lr = wr + i * 16 + lq * 4 + r;
                smP[lr] = pm[i][r];
                smN[lr] = nm[i][r];
            }
    }
    __syncthreads();
    if ((w & 1) == 0 && lm == 0) {
        #pragma unroll
        for (int i = 0; i < 4; ++i)
            #pragma unroll
            for (int r = 0; r < 4; ++r) {
                int lr = wr + i * 16 + lq * 4 + r;   // C/D: row = quad*4+reg
                smP[lr] = fmaxf(pm[i][r], smP[lr]);
                smN[lr] = fminf(nm[i][r], smN[lr]);
            }
    }
    __syncthreads();
    if (tid < 128) {                       // coalesced partial store
        pmp[(size_t)blockIdx.y * B + row0 + tid] = smP[tid];
        nmp[(size_t)blockIdx.y * B + row0 + tid] = smN[tid];
    }
}

// ---- kernel 3: per-row combine + hinge; atomic partials; last block divides ----
__global__ void reduce_kernel(const float* __restrict__ pmp, const float* __restrict__ nmp,
                              const float* __restrict__ rowterm, const int* __restrict__ target,
                              float* __restrict__ redsum, int* __restrict__ ticket,
                              float* __restrict__ out, int B) {
    int row = blockIdx.x * blockDim.x + threadIdx.x;    // 32 x 256 = 8192
    float s = 0.f, c = 0.f;
    {
        float pmv = -SENT, nmv = SENT;
        #pragma unroll 8
        for (int sp = 0; sp < SPLITS; ++sp) {
            pmv = fmaxf(pmv, pmp[(size_t)sp * B + row]);
            nmv = fminf(nmv, nmp[(size_t)sp * B + row]);
        }
        float rt = rowterm[row];
        float dp = sqrtf(fmaxf(rt + pmv, 0.f));
        float dn = sqrtf(fmaxf(rt + nmv, 0.f));
        if (target[row] == 1) {
            s = fmaxf(dp - dn + MARGIN, 0.f);
            c = 1.f;
        }
    }
    #pragma unroll
    for (int off = 32; off > 0; off >>= 1) {
        s += __shfl_down(s, off, 64);
        c += __shfl_down(c, off, 64);
    }
    __shared__ float ls[4], lc[4];
    int wv = threadIdx.x >> 6, ln = threadIdx.x & 63;
    if (ln == 0) { ls[wv] = s; lc[wv] = c; }
    __syncthreads();
    if (threadIdx.x == 0) {
        float ss = ls[0] + ls[1] + ls[2] + ls[3];
        float cc = lc[0] + lc[1] + lc[2] + lc[3];
        atomicAdd(&redsum[0], ss);
        atomicAdd(&redsum[1], cc);
        __threadfence();
        int done = atomicAdd(ticket, 1);
        if (done == (int)gridDim.x - 1) {
            __threadfence();
            float fs = __hip_atomic_load(&redsum[0], __ATOMIC_RELAXED, __HIP_MEMORY_SCOPE_AGENT);
            float fc = __hip_atomic_load(&redsum[1], __ATOMIC_RELAXED, __HIP_MEMORY_SCOPE_AGENT);
            out[0] = fs / fc;
        }
    }
}

extern "C" void kernel_launch(void* const* d_in, const int* in_sizes, int n_in,
                              void* d_out, int out_size, void* d_ws, size_t ws_size,
                              hipStream_t stream) {
    const float* e1     = (const float*)d_in[0];
    const float* e2     = (const float*)d_in[1];
    const int*   target = (const int*)d_in[2];
    float* out = (float*)d_out;
    const int B = in_sizes[2];                       // 8192

    // ws layout: e1b | e2b | rowterm | cpos | cneg | pmp | nmp | redsum | ticket
    char* p = (char*)d_ws;
    ushort_t* e1b  = (ushort_t*)p;   p += (size_t)B * DDIM * 2;   // 2 MB (scaled by -2)
    ushort_t* e2b  = (ushort_t*)p;   p += (size_t)B * DDIM * 2;   // 2 MB
    float* rowterm = (float*)p;      p += (size_t)B * 4;
    float* cpos    = (float*)p;      p += (size_t)B * 4;
    float* cneg    = (float*)p;      p += (size_t)B * 4;
    float* pmp     = (float*)p;      p += (size_t)SPLITS * B * 4; // 512 KB
    float* nmp     = (float*)p;      p += (size_t)SPLITS * B * 4; // 512 KB
    float* redsum  = (float*)p;      p += 2 * 4;
    int*   ticket  = (int*)p;

    {   // prep: 8 lanes/row, 32 rows/block -> 2B/32 = 512 blocks
        int blocks = (2 * B) / 32;
        prep_kernel<<<blocks, 256, 0, stream>>>(e1, e2, target, e1b, e2b,
                                                rowterm, cpos, cneg,
                                                redsum, ticket, B);
    }
    {   // 64 row-blocks x 16 col-splits = 1024 blocks; 37.9 KB LDS -> 3/CU
        dim3 grid(B / 128, SPLITS);
        tile_kernel<<<grid, 256, 0, stream>>>(e1b, e2b, cpos, cneg, pmp, nmp, B);
    }
    reduce_kernel<<<32, 256, 0, stream>>>(pmp, nmp, rowterm, target,
                                          redsum, ticket, out, B);
}

// Round 9
// 91.522 us; speedup vs baseline: 1.0347x; 1.0347x over previous
//
#include <hip/hip_runtime.h>
#include <hip/hip_bf16.h>
#include <math.h>

// Batch-hard triplet loss, B=8192, D=128, fp32 in.
// dist^2[i,j] = rowterm[i] + colterm[j] - 2*dot(e1[i], e2[j])
// sqrt & max/min commute -> track max/min of (colterm - 2*dot); dot on bf16
// matrix cores. Target folded into cpos/cneg (finite +-1e30 sentinels).
//
// R16 vs R14/R15: kill the REAL bank conflict. SQ_LDS_BANK_CONFLICT was
// 3,145,728 in R9, R11 AND R12 (identical!) -> R12's swizzle fixed nothing:
// position p = 2*(lm>>2) + (lq^(lm&3)) mod 8 puts 8 lanes on every 16B
// position ((lm&3)*256 aliases to 0 mod 128). +12 cyc on all 262K b128
// reads -> LDS pipe 24.6k cyc/CU = the LARGEST pipe term (MFMA 5.1k/SIMD,
// VALU 6.4k/SIMD). Fix by construction: B panel stored in FRAGMENT-ORDER
// [chunk(jj,k4)][lane][16B] (16 x 1KB chunks). DMA per-lane global source =
// the gather lane l <- B[jj*16+(l&15)][k4*32+(l>>4)*8] (16 rows x 64B
// segments, L2-fine); LDS write = DMA-native linear lane*16. Compute read =
// Bs + l*16 + chunk*1024: consecutive lanes/addresses = zero conflicts +
// one v-addr with imm offsets. Fragments element-identical -> absmax 0.
// Sync structure byte-identical to verified R14 (wait-then-barrier,
// vmcnt(4)); SPLITS=8 (best). LDS 40.9 KB.

#define DDIM   128
#define SPLITS 8
#define MARGIN 0.2f
#define EPS    1e-6f
#define SENT   1e30f

#define PANEL_BYTES  16384         // 16 chunks x 1024 B (64 cols x 128 K bf16)
#define CPCN_BYTES   (2048 * 4)    // 1024 cp + 1024 cn floats

typedef unsigned short ushort_t;
typedef __attribute__((ext_vector_type(8))) short short8;
typedef __attribute__((ext_vector_type(4))) float f32x4;
typedef __attribute__((ext_vector_type(4))) unsigned short ushort4_t;

__device__ __forceinline__ ushort_t f2bf(float f) {   // fp32 -> bf16 RNE
    unsigned int u = __float_as_uint(f);
    u = (u + 0x7FFFu + ((u >> 16) & 1u)) >> 16;
    return (ushort_t)u;
}

__device__ __forceinline__ void g2lds16(const void* g, void* lds) {
    // per-lane global src; wave-uniform lds base, lane i's 16 B at lds+i*16
    __builtin_amdgcn_global_load_lds(
        (const __attribute__((address_space(1))) unsigned int*)g,
        (__attribute__((address_space(3))) unsigned int*)lds,
        16, 0, 0);
}

// ---- kernel 1: bf16 convert + exact fp32 row stats + zero control vars ----
// 8 lanes per row; fully coalesced float4/ushort4. e1b stores bf16(-2*x)
// (exact scale: exp+1 & sign) so MFMA directly yields -2*dot.
__global__ void prep_kernel(const float* __restrict__ e1, const float* __restrict__ e2,
                            const int* __restrict__ target,
                            ushort_t* __restrict__ e1b, ushort_t* __restrict__ e2b,
                            float* __restrict__ rowterm,
                            float* __restrict__ cpos, float* __restrict__ cneg,
                            float* __restrict__ redsum, int* __restrict__ ticket, int B) {
    if (blockIdx.x == 0) {
        if (threadIdx.x == 0) { redsum[0] = 0.f; redsum[1] = 0.f; }
        else if (threadIdx.x == 1) *ticket = 0;
    }
    int gr  = blockIdx.x * 32 + (threadIdx.x >> 3);     // 0..2B-1
    int seg = threadIdx.x & 7;
    bool first = gr < B;
    int r = first ? gr : gr - B;
    const float* src = (first ? e1 : e2) + (size_t)r * DDIM;
    ushort_t*    dst = (first ? e1b : e2b) + (size_t)r * DDIM;
    const float sc = first ? -2.f : 1.f;
    float s = 0.f, n = 0.f;
    #pragma unroll
    for (int it = 0; it < 4; ++it) {
        int e0 = (seg + it * 8) * 4;
        float4 v = *(const float4*)(src + e0);
        ushort4_t o;
        o.x = f2bf(sc * v.x); o.y = f2bf(sc * v.y);
        o.z = f2bf(sc * v.z); o.w = f2bf(sc * v.w);
        *(ushort4_t*)(dst + e0) = o;
        s += v.x + v.y + v.z + v.w;
        n += v.x * v.x + v.y * v.y + v.z * v.z + v.w * v.w;
    }
    #pragma unroll
    for (int m = 1; m <= 4; m <<= 1) {                  // 8-lane group reduce
        s += __shfl_xor(s, m, 64);
        n += __shfl_xor(n, m, 64);
    }
    if (seg == 0) {
        if (first) {
            rowterm[r] = n + 2.f * EPS * s + (float)DDIM * EPS * EPS;
        } else {
            float ct = n - 2.f * EPS * s;
            int tg = target[r];
            cpos[r] = (tg == 1) ? ct : -SENT;
            cneg[r] = (tg == 0) ? ct :  SENT;
        }
    }
}

// stage a 64-col x 128-K bf16 panel in FRAGMENT ORDER. Wave w stages the 4
// chunks (jj=w, k4=0..3). Chunk (jj,k4) = the exact 64-lane MFMA B-fragment:
// lane l <- B[jj*16 + (l&15)][k4*32 + (l>>4)*8 .. +8] (16 B), landing at
// lds + (jj*4+k4)*1024 + l*16 (DMA-native linear write).
__device__ __forceinline__ void stage_panel(const ushort_t* __restrict__ pcol,
                                            unsigned char* __restrict__ lds,
                                            int w, int l) {
    const ushort_t* g = pcol + (size_t)(w * 16 + (l & 15)) * DDIM + (l >> 4) * 8;
    unsigned char* lp = lds + w * 4096;
    #pragma unroll
    for (int it = 0; it < 4; ++it)
        g2lds16(g + it * 32, lp + it * 1024);
}

// ---- kernel 2: streamed 64-col panels, counted-vmcnt pipeline -----------
// grid (B/128, SPLITS=8), block 256 = 4 waves. Block: 128 rows x 1024 cols
// as 16 panels of 64 cols, double-buffered. Wave w: rows (w>>1)*64..+64,
// cols (w&1)*32..+32 of each panel. A (K=128) in registers from L2.
__global__ __launch_bounds__(256, 3)
void tile_kernel(const ushort_t* __restrict__ e1b, const ushort_t* __restrict__ e2b,
                 const float* __restrict__ cpos, const float* __restrict__ cneg,
                 float* __restrict__ pmp, float* __restrict__ nmp, int B) {
    __shared__ __align__(16) unsigned char smRaw[2 * PANEL_BYTES + CPCN_BYTES];
    unsigned char* Bs0  = smRaw;
    unsigned char* Bs1  = smRaw + PANEL_BYTES;
    float*         smCp = (float*)(smRaw + 2 * PANEL_BYTES);   // [1024]
    float*         smCn = smCp + 1024;                          // [1024]

    const int tid = threadIdx.x;
    const int w   = tid >> 6;
    const int l   = tid & 63;
    const int lq  = l >> 4;          // quad 0..3
    const int lm  = l & 15;
    const int row0 = blockIdx.x * 128;
    const int col0 = blockIdx.y * 1024;
    const int nPanels = 16;

    const int wr = (w >> 1) * 64;    // wave's row half
    const int wc = (w & 1) * 32;     // wave's col half within 64-col panel
    const int jj0 = (w & 1) * 2;     // wave's first col-16-block within panel

    // prologue DMAs: panel 0 + cpos/cneg slabs (wave w -> 1 KB slice each)
    stage_panel(e2b + (size_t)col0 * DDIM, Bs0, w, l);
    g2lds16(cpos + col0 + w * 256 + l * 4, smCp + w * 256);
    g2lds16(cneg + col0 + w * 256 + l * 4, smCn + w * 256);

    // A fragments straight from global: row = row0+wr+i*16+lm,
    // elems [k4*32 + lq*8, +8). L2-resident (e1b = 2 MB, pre-scaled by -2).
    const ushort_t* aG = e1b + (size_t)(row0 + wr + lm) * DDIM + lq * 8;
    short8 afr[4][4];                // [i][k4]: 64 regs, K=128 resident
    #pragma unroll
    for (int i = 0; i < 4; ++i)
        #pragma unroll
        for (int k4 = 0; k4 < 4; ++k4)
            afr[i][k4] = *(const short8*)(aG + i * 16 * DDIM + k4 * 32);

    // B fragment read base: linear fragment-order layout -> per-lane base
    // Bs + l*16; chunk (jj,k4) at imm offset (jj*4+k4)*1024. Zero conflicts.
    const unsigned char* bLane = Bs0 + (size_t)l * 16;

    float pm[4][4], nm[4][4];        // [i][r]: local row = wr + i*16 + lq*4 + r
    #pragma unroll
    for (int i = 0; i < 4; ++i)
        #pragma unroll
        for (int r = 0; r < 4; ++r) { pm[i][r] = -SENT; nm[i][r] = SENT; }

    __syncthreads();   // full drain: panel 0 + cpcn + afr all resident

    for (int p = 0; p < nPanels; ++p) {
        // WAR barrier: all waves done READING panel p-1 -> its parity
        // buffer may now be overwritten by stage(p+1). (p=0: prologue
        // __syncthreads already synced.)
        if (p) __builtin_amdgcn_s_barrier();

        if (p + 1 < nPanels) {
            // issue next panel's DMA; vmcnt queue = [stage(p):4, stage(p+1):4]
            stage_panel(e2b + (size_t)(col0 + (p + 1) * 64) * DDIM,
                        (p & 1) ? Bs0 : Bs1, w, l);
            // retire exactly OWN stage(p) (4 oldest); stage(p+1) in flight
            asm volatile("s_waitcnt vmcnt(4)" ::: "memory");
        } else {
            asm volatile("s_waitcnt vmcnt(0)" ::: "memory");
        }
        // RAW barrier: every wave has retired ITS stage(p) loads, so the
        // whole panel p (all 4 waves' chunks) is resident before any read.
        __builtin_amdgcn_s_barrier();

        const unsigned char* bl = bLane + (p & 1) * PANEL_BYTES;

        f32x4 accA[4], accB[4];      // j=0 / j=1 accumulators (32 regs)
        #pragma unroll
        for (int i = 0; i < 4; ++i) {
            accA[i] = (f32x4){0.f, 0.f, 0.f, 0.f};
            accB[i] = (f32x4){0.f, 0.f, 0.f, 0.f};
        }

        #pragma unroll
        for (int k4 = 0; k4 < 4; ++k4) {
            const short8 b0 = *(const short8*)(bl + ((jj0 + 0) * 4 + k4) * 1024);
            const short8 b1 = *(const short8*)(bl + ((jj0 + 1) * 4 + k4) * 1024);
            #pragma unroll
            for (int i = 0; i < 4; ++i)
                accA[i] = __builtin_amdgcn_mfma_f32_16x16x32_bf16(
                              afr[i][k4], b0, accA[i], 0, 0, 0);
            #pragma unroll
            for (int i = 0; i < 4; ++i)
                accB[i] = __builtin_amdgcn_mfma_f32_16x16x32_bf16(
                              afr[i][k4], b1, accB[i], 0, 0, 0);
        }

        // epilogue: acc = -2*dot; colterm from LDS (lgkm only -> vmcnt
        // ledger stays pure). Paired so clang fuses v_max3/v_min3.
        {
            const int lcb = p * 64 + wc + lm;            // C/D: col = lane&15
            const float cp0 = smCp[lcb],      cn0 = smCn[lcb];
            const float cp1 = smCp[lcb + 16], cn1 = smCn[lcb + 16];
            #pragma unroll
            for (int i = 0; i < 4; ++i)
                #pragma unroll
                for (int r = 0; r < 4; ++r) {
                    const float d0 = accA[i][r];
                    const float d1 = accB[i][r];
                    pm[i][r] = fmaxf(fmaxf(pm[i][r], d0 + cp0), d1 + cp1);
                    nm[i][r] = fminf(fminf(nm[i][r], d0 + cn0), d1 + cn1);
                }
        }
    }

    // intra-wave: reduce across the 16 column-lanes (rows fixed per (lq,r))
    #pragma unroll
    for (int m = 1; m < 16; m <<= 1) {
        #pragma unroll
        for (int i = 0; i < 4; ++i)
            #pragma unroll
            for (int r = 0; r < 4; ++r) {
                pm[i][r] = fmaxf(pm[i][r], __shfl_xor(pm[i][r], m, 64));
                nm[i][r] = fminf(nm[i][r], __shfl_xor(nm[i][r], m, 64));
            }
    }

    // cross-wave: pairs (0,1),(2,3) share rows over complementary col halves.
    // Overlay on Bs0 (panel 15 lives in Bs1; Bs0's readers done at p=15's
    // WAR barrier). Even waves read only after the __syncthreads below.
    float* smP = (float*)smRaw;            // [128]
    float* smN = smP + 128;                // [128]
    if ((w & 1) == 1 && lm == 0) {
        #pragma unroll
        for (int i = 0; i < 4; ++i)
            #pragma unroll
            for (int r = 0; r < 4; ++r) {
                int lr = wr + i * 16 + lq * 4 + r;
                smP[lr] = pm[i][r];
                smN[lr] = nm[i][r];
            }
    }
    __syncthreads();
    if ((w & 1) == 0 && lm == 0) {
        #pragma unroll
        for (int i = 0; i < 4; ++i)
            #pragma unroll
            for (int r = 0; r < 4; ++r) {
                int lr = wr + i * 16 + lq * 4 + r;   // C/D: row = quad*4+reg
                smP[lr] = fmaxf(pm[i][r], smP[lr]);
                smN[lr] = fminf(nm[i][r], smN[lr]);
            }
    }
    __syncthreads();
    if (tid < 128) {                       // coalesced partial store
        pmp[(size_t)blockIdx.y * B + row0 + tid] = smP[tid];
        nmp[(size_t)blockIdx.y * B + row0 + tid] = smN[tid];
    }
}

// ---- kernel 3: per-row combine + hinge; atomic partials; last block divides ----
__global__ void reduce_kernel(const float* __restrict__ pmp, const float* __restrict__ nmp,
                              const float* __restrict__ rowterm, const int* __restrict__ target,
                              float* __restrict__ redsum, int* __restrict__ ticket,
                              float* __restrict__ out, int B) {
    int row = blockIdx.x * blockDim.x + threadIdx.x;    // 32 x 256 = 8192
    float s = 0.f, c = 0.f;
    {
        float pmv = -SENT, nmv = SENT;
        #pragma unroll
        for (int sp = 0; sp < SPLITS; ++sp) {
            pmv = fmaxf(pmv, pmp[(size_t)sp * B + row]);
            nmv = fminf(nmv, nmp[(size_t)sp * B + row]);
        }
        float rt = rowterm[row];
        float dp = sqrtf(fmaxf(rt + pmv, 0.f));
        float dn = sqrtf(fmaxf(rt + nmv, 0.f));
        if (target[row] == 1) {
            s = fmaxf(dp - dn + MARGIN, 0.f);
            c = 1.f;
        }
    }
    #pragma unroll
    for (int off = 32; off > 0; off >>= 1) {
        s += __shfl_down(s, off, 64);
        c += __shfl_down(c, off, 64);
    }
    __shared__ float ls[4], lc[4];
    int wv = threadIdx.x >> 6, ln = threadIdx.x & 63;
    if (ln == 0) { ls[wv] = s; lc[wv] = c; }
    __syncthreads();
    if (threadIdx.x == 0) {
        float ss = ls[0] + ls[1] + ls[2] + ls[3];
        float cc = lc[0] + lc[1] + lc[2] + lc[3];
        atomicAdd(&redsum[0], ss);
        atomicAdd(&redsum[1], cc);
        __threadfence();
        int done = atomicAdd(ticket, 1);
        if (done == (int)gridDim.x - 1) {
            __threadfence();
            float fs = __hip_atomic_load(&redsum[0], __ATOMIC_RELAXED, __HIP_MEMORY_SCOPE_AGENT);
            float fc = __hip_atomic_load(&redsum[1], __ATOMIC_RELAXED, __HIP_MEMORY_SCOPE_AGENT);
            out[0] = fs / fc;
        }
    }
}

extern "C" void kernel_launch(void* const* d_in, const int* in_sizes, int n_in,
                              void* d_out, int out_size, void* d_ws, size_t ws_size,
                              hipStream_t stream) {
    const float* e1     = (const float*)d_in[0];
    const float* e2     = (const float*)d_in[1];
    const int*   target = (const int*)d_in[2];
    float* out = (float*)d_out;
    const int B = in_sizes[2];                       // 8192

    // ws layout: e1b | e2b | rowterm | cpos | cneg | pmp | nmp | redsum | ticket
    char* p = (char*)d_ws;
    ushort_t* e1b  = (ushort_t*)p;   p += (size_t)B * DDIM * 2;   // 2 MB (scaled by -2)
    ushort_t* e2b  = (ushort_t*)p;   p += (size_t)B * DDIM * 2;   // 2 MB
    float* rowterm = (float*)p;      p += (size_t)B * 4;
    float* cpos    = (float*)p;      p += (size_t)B * 4;
    float* cneg    = (float*)p;      p += (size_t)B * 4;
    float* pmp     = (float*)p;      p += (size_t)SPLITS * B * 4; // 256 KB
    float* nmp     = (float*)p;      p += (size_t)SPLITS * B * 4; // 256 KB
    float* redsum  = (float*)p;      p += 2 * 4;
    int*   ticket  = (int*)p;

    {   // prep: 8 lanes/row, 32 rows/block -> 2B/32 = 512 blocks
        int blocks = (2 * B) / 32;
        prep_kernel<<<blocks, 256, 0, stream>>>(e1, e2, target, e1b, e2b,
                                                rowterm, cpos, cneg,
                                                redsum, ticket, B);
    }
    {   // 64 row-blocks x 8 col-splits = 512 blocks; 40.9 KB LDS, 3 waves/SIMD
        dim3 grid(B / 128, SPLITS);
        tile_kernel<<<grid, 256, 0, stream>>>(e1b, e2b, cpos, cneg, pmp, nmp, B);
    }
    reduce_kernel<<<32, 256, 0, stream>>>(pmp, nmp, rowterm, target,
                                          redsum, ticket, out, B);
}